// Round 15
// baseline (107.454 us; speedup 1.0000x reference)
//
#include <hip/hip_runtime.h>
#include <hip/hip_bf16.h>
#include <stdint.h>

#define NPAIRS 500000
#define NNODES 100000
#define DIM    128
#define D2     256

typedef __bf16 bf16;
typedef __bf16 bf16x8 __attribute__((ext_vector_type(8)));
typedef float  f32x4  __attribute__((ext_vector_type(4)));

// =================== pack W1 -> per-lane A-operand fragments ===================
// W1'[k][n'] = n'<256 ? W1[k][n'] (U half, k 0..127) : W1[k+128][n'-256] (V half)
__global__ void pack_w1p(const float* __restrict__ W1, bf16* __restrict__ w1p) {
    int t = blockIdx.x * 256 + threadIdx.x;   // 0..8191
    int lane = t & 63;
    int kks = (t >> 6) & 3;
    int cg  = t >> 8;                          // 0..31
    int l15 = lane & 15, lg = lane >> 4;
    int np = cg * 16 + l15;                    // 0..511
    int k0 = kks * 32 + lg * 8;
    const float* src = (np < D2) ? (W1 + (long)k0 * D2 + np)
                                 : (W1 + (long)(k0 + 128) * D2 + (np - D2));
    bf16x8 v;
#pragma unroll
    for (int j = 0; j < 8; ++j) v[j] = (bf16)src[(long)j * D2];
    *(bf16x8*)((char*)w1p + ((long)t << 4)) = v;
}

// ======= phase 1: UV8[node][512B] int8, Sq2[node][2] per-half scales =======
// 64 nodes/block (grid 1563), 8 waves. TWO passes of 256 hc (wave owns 32 hc,
// acc[2][4]); per pass: 32 contiguous MFMAs -> in-reg absmax (+2 shfl +
// LDS atomicMax) -> quantize -> 16KB hs16 -> 256B-burst copy-out. 7 syncs/tile.
__launch_bounds__(512, 8)
__global__ void gemm_uvq(const float* __restrict__ x,
                         const bf16*  __restrict__ w1p,
                         int8_t*      __restrict__ UV8,
                         float*       __restrict__ Sq2) {
    __shared__ char xt[64 * 256];     // 16 KB staged X (bf16, swizzled)
    __shared__ char hs16[64 * 256];   // 16 KB int8 half buffer (64 x 256 hc)
    __shared__ int  smx[64];          // per-node half absmax (float-as-int)
    int tid  = threadIdx.x;
    int wave = tid >> 6, lane = tid & 63;
    int l15 = lane & 15, lg = lane >> 4;
    long nb = (long)blockIdx.x * 64;

    if (tid < 64) smx[tid] = 0;       // pass-0 init (visible after stage sync)

    // stage 64 node rows fp32 -> bf16 (16 threads per 512B row, coalesced)
#pragma unroll
    for (int it = 0; it < 2; ++it) {
        int task = it * 512 + tid;          // 0..1023
        int r = task >> 4, c = task & 15;
        long node = nb + r;
        const float* src = x + (node < NNODES ? node : 0) * DIM + c * 8;
        float4 a = ((const float4*)src)[0];
        float4 b = ((const float4*)src)[1];
        bf16x8 v;
        v[0]=(bf16)a.x; v[1]=(bf16)a.y; v[2]=(bf16)a.z; v[3]=(bf16)a.w;
        v[4]=(bf16)b.x; v[5]=(bf16)b.y; v[6]=(bf16)b.z; v[7]=(bf16)b.w;
        *(bf16x8*)(xt + r * 256 + ((c * 16) ^ ((r & 15) << 4))) = v;
    }
    __syncthreads();

#pragma unroll 1
    for (int h = 0; h < 2; ++h) {
        f32x4 acc[2][4];
#pragma unroll
        for (int m = 0; m < 2; ++m)
#pragma unroll
            for (int nf = 0; nf < 4; ++nf)
                acc[m][nf] = (f32x4){0.f, 0.f, 0.f, 0.f};

        int cg0 = h * 16 + wave * 2;        // two 16-hc col groups per wave
#pragma unroll
        for (int kks = 0; kks < 4; ++kks) {
            bf16x8 wf0 = *(const bf16x8*)((const char*)w1p +
                             ((((cg0    ) * 4 + kks) * 64 + lane) << 4));
            bf16x8 wf1 = *(const bf16x8*)((const char*)w1p +
                             ((((cg0 + 1) * 4 + kks) * 64 + lane) << 4));
            int kbyte = kks * 64 + lg * 16;
#pragma unroll
            for (int nf = 0; nf < 4; ++nf) {
                int r = nf * 16 + l15;
                bf16x8 xf = *(const bf16x8*)(xt + r * 256 + (kbyte ^ ((r & 15) << 4)));
                acc[0][nf] = __builtin_amdgcn_mfma_f32_16x16x32_bf16(wf0, xf, acc[0][nf], 0, 0, 0);
                acc[1][nf] = __builtin_amdgcn_mfma_f32_16x16x32_bf16(wf1, xf, acc[1][nf], 0, 0, 0);
            }
        }
        __syncthreads();   // smx zeroed visible; prev-pass hs16 copy-out done

        // per-row half absmax: 8 lane-local values, 2 indep shfl, lg==0 atomicMax
#pragma unroll
        for (int nf = 0; nf < 4; ++nf) {
            float m = fmaxf(
                fmaxf(fmaxf(fabsf(acc[0][nf][0]), fabsf(acc[0][nf][1])),
                      fmaxf(fabsf(acc[0][nf][2]), fabsf(acc[0][nf][3]))),
                fmaxf(fmaxf(fabsf(acc[1][nf][0]), fabsf(acc[1][nf][1])),
                      fmaxf(fabsf(acc[1][nf][2]), fabsf(acc[1][nf][3]))));
            m = fmaxf(m, __shfl_xor(m, 16));
            m = fmaxf(m, __shfl_xor(m, 32));
            if (lg == 0) atomicMax(&smx[nf * 16 + l15], __float_as_int(m));
        }
        __syncthreads();

        // quantize from registers, 4B swizzled writes into hs16
#pragma unroll
        for (int nf = 0; nf < 4; ++nf) {
            int row = nf * 16 + l15;
            float m2 = __int_as_float(smx[row]);
            float rs = (m2 > 1e-20f) ? 127.0f * __builtin_amdgcn_rcpf(m2) : 0.f;
#pragma unroll
            for (int m = 0; m < 2; ++m) {
                uint32_t packed = 0;
#pragma unroll
                for (int r = 0; r < 4; ++r) {
                    int q = (int)__builtin_rintf(acc[m][nf][r] * rs);
                    q = q > 127 ? 127 : (q < -127 ? -127 : q);
                    packed |= ((uint32_t)(q & 255)) << (8 * r);
                }
                int col = (wave * 32 + m * 16 + lg * 4) ^ ((row & 15) << 4);
                *(uint32_t*)(hs16 + row * 256 + col) = packed;
            }
        }
        __syncthreads();

        // copy-out: 1024 tasks x 16B; 256B contiguous per node row; + scales
#pragma unroll
        for (int it = 0; it < 2; ++it) {
            int ci = it * 512 + tid;         // 0..1023
            int row = ci >> 4, c16 = (ci & 15) << 4;
            uint4 v = *(const uint4*)(hs16 + row * 256 + (c16 ^ ((row & 15) << 4)));
            long node = nb + row;
            if (node < NNODES)
                *(uint4*)((char*)UV8 + node * 512 + h * 256 + c16) = v;
        }
        if (tid < 64) {
            long node = nb + tid;
            if (node < NNODES)
                Sq2[node * 2 + h] = __int_as_float(smx[tid]) * (1.0f / 127.0f);
            smx[tid] = 0;                   // re-init for pass 1 (same-thread ordered)
        }
        // next pass's post-MFMA sync orders hs16/smx reuse
    }
}

// =================== phase 2: pred = W2.relu(su*u8 + sv*v8 + b1) + b2 ===================
// 4 pairs per wave (16 lanes each); lane loads 16B of u and v (16 hc).
__launch_bounds__(512)
__global__ void pair_pred8(const int8_t* __restrict__ UV8,
                           const float* __restrict__ Sq2,
                           const int* __restrict__ junc,
                           const float* __restrict__ b1, const float* __restrict__ w2,
                           const float* __restrict__ b2, float* __restrict__ out) {
    int tid = threadIdx.x;
    int l15 = tid & 15;
    long qid = (((long)blockIdx.x * 512 + tid) >> 4);   // 0..32767
    float b1c[16], w2c[16];
#pragma unroll
    for (int e = 0; e < 16; ++e) {
        int col = l15 * 16 + e;
        b1c[e] = b1[col];
        w2c[e] = w2[col];
    }
    float b2v = b2[0];
    for (long p = qid; p < NPAIRS; p += 32768) {
        int2 ij = ((const int2*)junc)[p];
        uint4 u4 = *(const uint4*)(UV8 + (long)ij.x * 512 + l15 * 16);
        uint4 v4 = *(const uint4*)(UV8 + (long)ij.y * 512 + 256 + l15 * 16);
        float su = Sq2[ij.x * 2];
        float sv = Sq2[ij.y * 2 + 1];
        float s = 0.f;
#define DEC(ud, vd, eb)                                                        \
        {                                                                      \
            _Pragma("unroll")                                                  \
            for (int b = 0; b < 4; ++b) {                                      \
                int ub = (int)((ud) << (24 - 8 * b)) >> 24;                    \
                int vb = (int)((vd) << (24 - 8 * b)) >> 24;                    \
                float h = fmaf(su, (float)ub, fmaf(sv, (float)vb, b1c[(eb) + b])); \
                s = fmaf(fmaxf(h, 0.f), w2c[(eb) + b], s);                     \
            }                                                                  \
        }
        DEC(u4.x, v4.x, 0)
        DEC(u4.y, v4.y, 4)
        DEC(u4.z, v4.z, 8)
        DEC(u4.w, v4.w, 12)
#undef DEC
        s += __shfl_xor(s, 1);
        s += __shfl_xor(s, 2);
        s += __shfl_xor(s, 4);
        s += __shfl_xor(s, 8);
        if (l15 == 0) out[p] = s + b2v;
    }
}

// =================== fallback (small ws): fused, known-correct ===================
__global__ void pack_w1(const float* __restrict__ W1, bf16* __restrict__ w1f) {
    int t = blockIdx.x * 256 + threadIdx.x;
    int lane = t & 63;
    int kk = (t >> 6) & 7;
    int cg = t >> 9;
    int l15 = lane & 15, lg = lane >> 4;
    bf16x8 v;
#pragma unroll
    for (int j = 0; j < 8; ++j)
        v[j] = (bf16)W1[(long)(kk * 32 + lg * 8 + j) * D2 + cg * 16 + l15];
    *(bf16x8*)((char*)w1f + ((long)t << 4)) = v;
}

__launch_bounds__(512, 2)
__global__ void fused_fb(const float* __restrict__ x, const int* __restrict__ junc,
                         const bf16* __restrict__ w1f, const float* __restrict__ b1,
                         const float* __restrict__ w2p, const float* __restrict__ b2,
                         float* __restrict__ out) {
    __shared__ char  atile[128 * 512];
    __shared__ float outp[4][128];
    int tid  = threadIdx.x;
    int wave = tid >> 6, lane = tid & 63;
    int l15 = lane & 15, lg = lane >> 4;
    int wr = wave >> 2, wc = wave & 3;
    long base_p = (long)blockIdx.x * 128;

    float bb[4][4], ww[4][4];
#pragma unroll
    for (int m = 0; m < 4; ++m)
#pragma unroll
        for (int r = 0; r < 4; ++r) {
            int hc = wc * 64 + m * 16 + lg * 4 + r;
            bb[m][r] = b1[hc];
            ww[m][r] = w2p[hc];
        }
#pragma unroll
    for (int it = 0; it < 8; ++it) {
        int task  = it * 512 + tid;
        int nr = task >> 4, chunk = task & 15;
        int r = nr >> 1, side = nr & 1;
        long p = base_p + r;
        int idx = (p < NPAIRS) ? junc[p * 2 + side] : 0;
        const float4* src = (const float4*)(x + (long)idx * DIM + chunk * 8);
        float4 a = src[0], b = src[1];
        bf16x8 v;
        v[0]=(bf16)a.x; v[1]=(bf16)a.y; v[2]=(bf16)a.z; v[3]=(bf16)a.w;
        v[4]=(bf16)b.x; v[5]=(bf16)b.y; v[6]=(bf16)b.z; v[7]=(bf16)b.w;
        int bir = side * 256 + chunk * 16;
        *(bf16x8*)(atile + r * 512 + (bir ^ ((r & 31) << 4))) = v;
    }
    __syncthreads();

    f32x4 acc[4][4];
#pragma unroll
    for (int m = 0; m < 4; ++m)
#pragma unroll
        for (int n = 0; n < 4; ++n)
            acc[m][n] = (f32x4){0.f, 0.f, 0.f, 0.f};
#pragma unroll
    for (int kk = 0; kk < 8; ++kk) {
        bf16x8 xf[4];
        int kbyte = kk * 64 + lg * 16;
#pragma unroll
        for (int n = 0; n < 4; ++n) {
            int r = wr * 64 + n * 16 + l15;
            xf[n] = *(const bf16x8*)(atile + r * 512 + (kbyte ^ ((r & 31) << 4)));
        }
#pragma unroll
        for (int m = 0; m < 4; ++m) {
            bf16x8 wf = *(const bf16x8*)((const char*)w1f +
                            ((((wc * 4 + m) * 8 + kk) * 64 + lane) << 4));
#pragma unroll
            for (int n = 0; n < 4; ++n)
                acc[m][n] = __builtin_amdgcn_mfma_f32_16x16x32_bf16(wf, xf[n], acc[m][n], 0, 0, 0);
        }
    }
#pragma unroll
    for (int n = 0; n < 4; ++n) {
        float s = 0.f;
#pragma unroll
        for (int m = 0; m < 4; ++m)
#pragma unroll
            for (int r = 0; r < 4; ++r)
                s = fmaf(fmaxf(acc[m][n][r] + bb[m][r], 0.f), ww[m][r], s);
        s += __shfl_xor(s, 16);
        s += __shfl_xor(s, 32);
        if (lg == 0) outp[wc][wr * 64 + n * 16 + l15] = s;
    }
    __syncthreads();
    if (tid < 128) {
        long p = base_p + tid;
        if (p < NPAIRS)
            out[p] = b2[0] + outp[0][tid] + outp[1][tid] + outp[2][tid] + outp[3][tid];
    }
}

extern "C" void kernel_launch(void* const* d_in, const int* in_sizes, int n_in,
                              void* d_out, int out_size, void* d_ws, size_t ws_size,
                              hipStream_t stream) {
    const float* x    = (const float*)d_in[0];
    const int*   junc = (const int*)  d_in[1];
    const float* W1   = (const float*)d_in[2];
    const float* b1   = (const float*)d_in[3];
    const float* W2   = (const float*)d_in[4];
    const float* b2   = (const float*)d_in[5];
    float* out = (float*)d_out;

    const size_t UV8_B = (size_t)NNODES * 512;        // 51,200,000
    const size_t SQ_B  = (size_t)NNODES * 8;          // 800,000
    const size_t NEED  = UV8_B + SQ_B + 131072;       // ~52.1 MB

    if (ws_size >= NEED) {
        char* base = (char*)d_ws;
        int8_t* UV8 = (int8_t*)base;
        float*  Sq2 = (float*)(base + UV8_B);
        bf16*   w1p = (bf16*) (base + UV8_B + SQ_B);
        hipLaunchKernelGGL(pack_w1p, dim3(32), dim3(256), 0, stream, W1, w1p);
        hipLaunchKernelGGL(gemm_uvq, dim3((NNODES + 63) / 64), dim3(512), 0, stream,
                           x, w1p, UV8, Sq2);
        hipLaunchKernelGGL(pair_pred8, dim3(1024), dim3(512), 0, stream,
                           UV8, Sq2, junc, b1, W2, b2, out);
    } else {
        bf16* w1f = (bf16*)d_ws;
        hipLaunchKernelGGL(pack_w1, dim3(32), dim3(256), 0, stream, W1, w1f);
        hipLaunchKernelGGL(fused_fb, dim3((NPAIRS + 127) / 128), dim3(512), 0, stream,
                           x, junc, w1f, b1, W2, b2, out);
    }
}

// Round 16
// 97.359 us; speedup vs baseline: 1.1037x; 1.1037x over previous
//
#include <hip/hip_runtime.h>
#include <hip/hip_bf16.h>
#include <stdint.h>

#define NPAIRS 500000
#define NNODES 100000
#define DIM    128
#define D2     256

typedef __bf16 bf16;
typedef __bf16 bf16x8 __attribute__((ext_vector_type(8)));
typedef float  f32x4  __attribute__((ext_vector_type(4)));

// =================== pack W1 -> per-lane A-operand fragments ===================
// W1'[k][n'] = n'<256 ? W1[k][n'] (U half, k 0..127) : W1[k+128][n'-256] (V half)
__global__ void pack_w1p(const float* __restrict__ W1, bf16* __restrict__ w1p) {
    int t = blockIdx.x * 256 + threadIdx.x;   // 0..8191
    int lane = t & 63;
    int kks = (t >> 6) & 3;
    int cg  = t >> 8;                          // 0..31
    int l15 = lane & 15, lg = lane >> 4;
    int np = cg * 16 + l15;                    // 0..511
    int k0 = kks * 32 + lg * 8;
    const float* src = (np < D2) ? (W1 + (long)k0 * D2 + np)
                                 : (W1 + (long)(k0 + 128) * D2 + (np - D2));
    bf16x8 v;
#pragma unroll
    for (int j = 0; j < 8; ++j) v[j] = (bf16)src[(long)j * D2];
    *(bf16x8*)((char*)w1p + ((long)t << 4)) = v;
}

// ======= phase 1: UV8[node][512B] int8, Sq2[node][2] per-half scales =======
// 64 nodes/block (grid 1563), 8 waves, TWO passes of 256 hc (acc[2][4]).
// lb(512,6): VGPR cap ~80 so the ~75-reg live set fits WITHOUT scratch spill
// (lb(512,8)'s 64-cap spilled: round-15 WRITE_SIZE 130MB). 7 syncs/tile.
__launch_bounds__(512, 6)
__global__ void gemm_uvq(const float* __restrict__ x,
                         const bf16*  __restrict__ w1p,
                         int8_t*      __restrict__ UV8,
                         float*       __restrict__ Sq2) {
    __shared__ char xt[64 * 256];     // 16 KB staged X (bf16, swizzled)
    __shared__ char hs16[64 * 256];   // 16 KB int8 half buffer (64 x 256 hc)
    __shared__ int  smx[64];          // per-node half absmax (float-as-int)
    int tid  = threadIdx.x;
    int wave = tid >> 6, lane = tid & 63;
    int l15 = lane & 15, lg = lane >> 4;
    long nb = (long)blockIdx.x * 64;

    if (tid < 64) smx[tid] = 0;       // pass-0 init (visible after stage sync)

    // stage 64 node rows fp32 -> bf16 (16 threads per 512B row, coalesced)
#pragma unroll
    for (int it = 0; it < 2; ++it) {
        int task = it * 512 + tid;          // 0..1023
        int r = task >> 4, c = task & 15;
        long node = nb + r;
        const float* src = x + (node < NNODES ? node : 0) * DIM + c * 8;
        float4 a = ((const float4*)src)[0];
        float4 b = ((const float4*)src)[1];
        bf16x8 v;
        v[0]=(bf16)a.x; v[1]=(bf16)a.y; v[2]=(bf16)a.z; v[3]=(bf16)a.w;
        v[4]=(bf16)b.x; v[5]=(bf16)b.y; v[6]=(bf16)b.z; v[7]=(bf16)b.w;
        *(bf16x8*)(xt + r * 256 + ((c * 16) ^ ((r & 15) << 4))) = v;
    }
    __syncthreads();

#pragma unroll 1
    for (int h = 0; h < 2; ++h) {
        f32x4 acc[2][4];
#pragma unroll
        for (int m = 0; m < 2; ++m)
#pragma unroll
            for (int nf = 0; nf < 4; ++nf)
                acc[m][nf] = (f32x4){0.f, 0.f, 0.f, 0.f};

        int cg0 = h * 16 + wave * 2;        // two 16-hc col groups per wave
#pragma unroll
        for (int kks = 0; kks < 4; ++kks) {
            bf16x8 wf0 = *(const bf16x8*)((const char*)w1p +
                             ((((cg0    ) * 4 + kks) * 64 + lane) << 4));
            bf16x8 wf1 = *(const bf16x8*)((const char*)w1p +
                             ((((cg0 + 1) * 4 + kks) * 64 + lane) << 4));
            int kbyte = kks * 64 + lg * 16;
#pragma unroll
            for (int nf = 0; nf < 4; ++nf) {
                int r = nf * 16 + l15;
                bf16x8 xf = *(const bf16x8*)(xt + r * 256 + (kbyte ^ ((r & 15) << 4)));
                acc[0][nf] = __builtin_amdgcn_mfma_f32_16x16x32_bf16(wf0, xf, acc[0][nf], 0, 0, 0);
                acc[1][nf] = __builtin_amdgcn_mfma_f32_16x16x32_bf16(wf1, xf, acc[1][nf], 0, 0, 0);
            }
        }
        __syncthreads();   // smx zeroed visible; prev-pass hs16 copy-out done

        // per-row half absmax: 8 lane-local values, 2 indep shfl, lg==0 atomicMax
#pragma unroll
        for (int nf = 0; nf < 4; ++nf) {
            float m = fmaxf(
                fmaxf(fmaxf(fabsf(acc[0][nf][0]), fabsf(acc[0][nf][1])),
                      fmaxf(fabsf(acc[0][nf][2]), fabsf(acc[0][nf][3]))),
                fmaxf(fmaxf(fabsf(acc[1][nf][0]), fabsf(acc[1][nf][1])),
                      fmaxf(fabsf(acc[1][nf][2]), fabsf(acc[1][nf][3]))));
            m = fmaxf(m, __shfl_xor(m, 16));
            m = fmaxf(m, __shfl_xor(m, 32));
            if (lg == 0) atomicMax(&smx[nf * 16 + l15], __float_as_int(m));
        }
        __syncthreads();

        // quantize from registers, 4B swizzled writes into hs16
#pragma unroll
        for (int nf = 0; nf < 4; ++nf) {
            int row = nf * 16 + l15;
            float m2 = __int_as_float(smx[row]);
            float rs = (m2 > 1e-20f) ? 127.0f * __builtin_amdgcn_rcpf(m2) : 0.f;
#pragma unroll
            for (int m = 0; m < 2; ++m) {
                uint32_t packed = 0;
#pragma unroll
                for (int r = 0; r < 4; ++r) {
                    int q = (int)__builtin_rintf(acc[m][nf][r] * rs);
                    q = q > 127 ? 127 : (q < -127 ? -127 : q);
                    packed |= ((uint32_t)(q & 255)) << (8 * r);
                }
                int col = (wave * 32 + m * 16 + lg * 4) ^ ((row & 15) << 4);
                *(uint32_t*)(hs16 + row * 256 + col) = packed;
            }
        }
        __syncthreads();

        // copy-out: 1024 tasks x 16B; 256B contiguous per node row; + scales
#pragma unroll
        for (int it = 0; it < 2; ++it) {
            int ci = it * 512 + tid;         // 0..1023
            int row = ci >> 4, c16 = (ci & 15) << 4;
            uint4 v = *(const uint4*)(hs16 + row * 256 + (c16 ^ ((row & 15) << 4)));
            long node = nb + row;
            if (node < NNODES)
                *(uint4*)((char*)UV8 + node * 512 + h * 256 + c16) = v;
        }
        if (tid < 64) {
            long node = nb + tid;
            if (node < NNODES)
                Sq2[node * 2 + h] = __int_as_float(smx[tid]) * (1.0f / 127.0f);
            smx[tid] = 0;                   // re-init for pass 1 (same-thread ordered)
        }
        // next pass's post-MFMA sync orders hs16/smx reuse
    }
}

// =================== phase 2: pred = W2.relu(su*u8 + sv*v8 + b1) + b2 ===================
// 4 pairs per wave (16 lanes each); lane loads 16B of u and v (16 hc).
__launch_bounds__(512)
__global__ void pair_pred8(const int8_t* __restrict__ UV8,
                           const float* __restrict__ Sq2,
                           const int* __restrict__ junc,
                           const float* __restrict__ b1, const float* __restrict__ w2,
                           const float* __restrict__ b2, float* __restrict__ out) {
    int tid = threadIdx.x;
    int l15 = tid & 15;
    long qid = (((long)blockIdx.x * 512 + tid) >> 4);   // 0..32767
    float b1c[16], w2c[16];
#pragma unroll
    for (int e = 0; e < 16; ++e) {
        int col = l15 * 16 + e;
        b1c[e] = b1[col];
        w2c[e] = w2[col];
    }
    float b2v = b2[0];
    for (long p = qid; p < NPAIRS; p += 32768) {
        int2 ij = ((const int2*)junc)[p];
        uint4 u4 = *(const uint4*)(UV8 + (long)ij.x * 512 + l15 * 16);
        uint4 v4 = *(const uint4*)(UV8 + (long)ij.y * 512 + 256 + l15 * 16);
        float su = Sq2[ij.x * 2];
        float sv = Sq2[ij.y * 2 + 1];
        float s = 0.f;
#define DEC(ud, vd, eb)                                                        \
        {                                                                      \
            _Pragma("unroll")                                                  \
            for (int b = 0; b < 4; ++b) {                                      \
                int ub = (int)((ud) << (24 - 8 * b)) >> 24;                    \
                int vb = (int)((vd) << (24 - 8 * b)) >> 24;                    \
                float h = fmaf(su, (float)ub, fmaf(sv, (float)vb, b1c[(eb) + b])); \
                s = fmaf(fmaxf(h, 0.f), w2c[(eb) + b], s);                     \
            }                                                                  \
        }
        DEC(u4.x, v4.x, 0)
        DEC(u4.y, v4.y, 4)
        DEC(u4.z, v4.z, 8)
        DEC(u4.w, v4.w, 12)
#undef DEC
        s += __shfl_xor(s, 1);
        s += __shfl_xor(s, 2);
        s += __shfl_xor(s, 4);
        s += __shfl_xor(s, 8);
        if (l15 == 0) out[p] = s + b2v;
    }
}

// =================== fallback (small ws): fused, known-correct ===================
__global__ void pack_w1(const float* __restrict__ W1, bf16* __restrict__ w1f) {
    int t = blockIdx.x * 256 + threadIdx.x;
    int lane = t & 63;
    int kk = (t >> 6) & 7;
    int cg = t >> 9;
    int l15 = lane & 15, lg = lane >> 4;
    bf16x8 v;
#pragma unroll
    for (int j = 0; j < 8; ++j)
        v[j] = (bf16)W1[(long)(kk * 32 + lg * 8 + j) * D2 + cg * 16 + l15];
    *(bf16x8*)((char*)w1f + ((long)t << 4)) = v;
}

__launch_bounds__(512, 2)
__global__ void fused_fb(const float* __restrict__ x, const int* __restrict__ junc,
                         const bf16* __restrict__ w1f, const float* __restrict__ b1,
                         const float* __restrict__ w2p, const float* __restrict__ b2,
                         float* __restrict__ out) {
    __shared__ char  atile[128 * 512];
    __shared__ float outp[4][128];
    int tid  = threadIdx.x;
    int wave = tid >> 6, lane = tid & 63;
    int l15 = lane & 15, lg = lane >> 4;
    int wr = wave >> 2, wc = wave & 3;
    long base_p = (long)blockIdx.x * 128;

    float bb[4][4], ww[4][4];
#pragma unroll
    for (int m = 0; m < 4; ++m)
#pragma unroll
        for (int r = 0; r < 4; ++r) {
            int hc = wc * 64 + m * 16 + lg * 4 + r;
            bb[m][r] = b1[hc];
            ww[m][r] = w2p[hc];
        }
#pragma unroll
    for (int it = 0; it < 8; ++it) {
        int task  = it * 512 + tid;
        int nr = task >> 4, chunk = task & 15;
        int r = nr >> 1, side = nr & 1;
        long p = base_p + r;
        int idx = (p < NPAIRS) ? junc[p * 2 + side] : 0;
        const float4* src = (const float4*)(x + (long)idx * DIM + chunk * 8);
        float4 a = src[0], b = src[1];
        bf16x8 v;
        v[0]=(bf16)a.x; v[1]=(bf16)a.y; v[2]=(bf16)a.z; v[3]=(bf16)a.w;
        v[4]=(bf16)b.x; v[5]=(bf16)b.y; v[6]=(bf16)b.z; v[7]=(bf16)b.w;
        int bir = side * 256 + chunk * 16;
        *(bf16x8*)(atile + r * 512 + (bir ^ ((r & 31) << 4))) = v;
    }
    __syncthreads();

    f32x4 acc[4][4];
#pragma unroll
    for (int m = 0; m < 4; ++m)
#pragma unroll
        for (int n = 0; n < 4; ++n)
            acc[m][n] = (f32x4){0.f, 0.f, 0.f, 0.f};
#pragma unroll
    for (int kk = 0; kk < 8; ++kk) {
        bf16x8 xf[4];
        int kbyte = kk * 64 + lg * 16;
#pragma unroll
        for (int n = 0; n < 4; ++n) {
            int r = wr * 64 + n * 16 + l15;
            xf[n] = *(const bf16x8*)(atile + r * 512 + (kbyte ^ ((r & 31) << 4)));
        }
#pragma unroll
        for (int m = 0; m < 4; ++m) {
            bf16x8 wf = *(const bf16x8*)((const char*)w1f +
                            ((((wc * 4 + m) * 8 + kk) * 64 + lane) << 4));
#pragma unroll
            for (int n = 0; n < 4; ++n)
                acc[m][n] = __builtin_amdgcn_mfma_f32_16x16x32_bf16(wf, xf[n], acc[m][n], 0, 0, 0);
        }
    }
#pragma unroll
    for (int n = 0; n < 4; ++n) {
        float s = 0.f;
#pragma unroll
        for (int m = 0; m < 4; ++m)
#pragma unroll
            for (int r = 0; r < 4; ++r)
                s = fmaf(fmaxf(acc[m][n][r] + bb[m][r], 0.f), ww[m][r], s);
        s += __shfl_xor(s, 16);
        s += __shfl_xor(s, 32);
        if (lg == 0) outp[wc][wr * 64 + n * 16 + l15] = s;
    }
    __syncthreads();
    if (tid < 128) {
        long p = base_p + tid;
        if (p < NPAIRS)
            out[p] = b2[0] + outp[0][tid] + outp[1][tid] + outp[2][tid] + outp[3][tid];
    }
}

extern "C" void kernel_launch(void* const* d_in, const int* in_sizes, int n_in,
                              void* d_out, int out_size, void* d_ws, size_t ws_size,
                              hipStream_t stream) {
    const float* x    = (const float*)d_in[0];
    const int*   junc = (const int*)  d_in[1];
    const float* W1   = (const float*)d_in[2];
    const float* b1   = (const float*)d_in[3];
    const float* W2   = (const float*)d_in[4];
    const float* b2   = (const float*)d_in[5];
    float* out = (float*)d_out;

    const size_t UV8_B = (size_t)NNODES * 512;        // 51,200,000
    const size_t SQ_B  = (size_t)NNODES * 8;          // 800,000
    const size_t NEED  = UV8_B + SQ_B + 131072;       // ~52.1 MB

    if (ws_size >= NEED) {
        char* base = (char*)d_ws;
        int8_t* UV8 = (int8_t*)base;
        float*  Sq2 = (float*)(base + UV8_B);
        bf16*   w1p = (bf16*) (base + UV8_B + SQ_B);
        hipLaunchKernelGGL(pack_w1p, dim3(32), dim3(256), 0, stream, W1, w1p);
        hipLaunchKernelGGL(gemm_uvq, dim3((NNODES + 63) / 64), dim3(512), 0, stream,
                           x, w1p, UV8, Sq2);
        hipLaunchKernelGGL(pair_pred8, dim3(1024), dim3(512), 0, stream,
                           UV8, Sq2, junc, b1, W2, b2, out);
    } else {
        bf16* w1f = (bf16*)d_ws;
        hipLaunchKernelGGL(pack_w1, dim3(32), dim3(256), 0, stream, W1, w1f);
        hipLaunchKernelGGL(fused_fb, dim3((NPAIRS + 127) / 128), dim3(512), 0, stream,
                           x, junc, w1f, b1, W2, b2, out);
    }
}

// Round 19
// 93.418 us; speedup vs baseline: 1.1503x; 1.0422x over previous
//
#include <hip/hip_runtime.h>
#include <hip/hip_bf16.h>
#include <stdint.h>

#define NPAIRS 500000
#define NNODES 100000
#define DIM    128
#define D2     256

typedef __bf16 bf16;
typedef __bf16 bf16x8 __attribute__((ext_vector_type(8)));
typedef float  f32x4  __attribute__((ext_vector_type(4)));

// =================== pack W1 -> per-lane A-operand fragments ===================
// W1'[k][n'] = n'<256 ? W1[k][n'] (U half, k 0..127) : W1[k+128][n'-256] (V half)
__global__ void pack_w1p(const float* __restrict__ W1, bf16* __restrict__ w1p) {
    int t = blockIdx.x * 256 + threadIdx.x;   // 0..8191
    int lane = t & 63;
    int kks = (t >> 6) & 3;
    int cg  = t >> 8;                          // 0..31
    int l15 = lane & 15, lg = lane >> 4;
    int np = cg * 16 + l15;                    // 0..511
    int k0 = kks * 32 + lg * 8;
    const float* src = (np < D2) ? (W1 + (long)k0 * D2 + np)
                                 : (W1 + (long)(k0 + 128) * D2 + (np - D2));
    bf16x8 v;
#pragma unroll
    for (int j = 0; j < 8; ++j) v[j] = (bf16)src[(long)j * D2];
    *(bf16x8*)((char*)w1p + ((long)t << 4)) = v;
}

// =================== phase 1: UV8[node][512B] int8 + Sq[node][4] stripe scales =========
// round-9 skeleton; quantize fully in-register: 2 indep shfl + LDS atomicMax for the
// 128-hc stripe max, rcp-quantize from f32 acc, 4B swizzled write to 8KB int8 hs,
// 16B/lane coalesced copy-out.  [measured: 93.7us total, gemm ~38us, round 14]
__launch_bounds__(512, 8)
__global__ void gemm_uvq(const float* __restrict__ x,
                         const bf16*  __restrict__ w1p,
                         int8_t*      __restrict__ UV8,
                         float*       __restrict__ Sq) {
    __shared__ char xt[64 * 256];    // 16 KB staged X (bf16, swizzled)
    __shared__ char hs8[64 * 128];   // 8 KB int8 stripe buffer
    __shared__ int  smx[64];         // per-node stripe absmax (float-as-int)
    int tid  = threadIdx.x;
    int wave = tid >> 6, lane = tid & 63;
    int l15 = lane & 15, lg = lane >> 4;
    long nb = (long)blockIdx.x * 64;

    // stage 64 node rows fp32 -> bf16 (16 threads per 512B row, coalesced)
#pragma unroll
    for (int it = 0; it < 2; ++it) {
        int task = it * 512 + tid;          // 0..1023
        int r = task >> 4, c = task & 15;
        long node = nb + r;
        const float* src = x + (node < NNODES ? node : 0) * DIM + c * 8;
        float4 a = ((const float4*)src)[0];
        float4 b = ((const float4*)src)[1];
        bf16x8 v;
        v[0]=(bf16)a.x; v[1]=(bf16)a.y; v[2]=(bf16)a.z; v[3]=(bf16)a.w;
        v[4]=(bf16)b.x; v[5]=(bf16)b.y; v[6]=(bf16)b.z; v[7]=(bf16)b.w;
        *(bf16x8*)(xt + r * 256 + ((c * 16) ^ ((r & 15) << 4))) = v;
    }
    __syncthreads();

#pragma unroll 1
    for (int p = 0; p < 4; ++p) {
        if (tid < 64) smx[tid] = 0;          // re-init (same-thread ordered vs prior read)

        f32x4 acc[4];
#pragma unroll
        for (int nf = 0; nf < 4; ++nf) acc[nf] = (f32x4){0.f, 0.f, 0.f, 0.f};

        int cg = p * 8 + wave;
#pragma unroll
        for (int kks = 0; kks < 4; ++kks) {
            bf16x8 wf = *(const bf16x8*)((const char*)w1p +
                            (((cg * 4 + kks) * 64 + lane) << 4));
            int kbyte = kks * 64 + lg * 16;
#pragma unroll
            for (int nf = 0; nf < 4; ++nf) {
                int r = nf * 16 + l15;
                bf16x8 xf = *(const bf16x8*)(xt + r * 256 + (kbyte ^ ((r & 15) << 4)));
                acc[nf] = __builtin_amdgcn_mfma_f32_16x16x32_bf16(wf, xf, acc[nf], 0, 0, 0);
            }
        }
        __syncthreads();    // smx init visible; prev pass hs8 copy-out complete

        // stripe max: lane-local (3 fmax) + 2 indep shfl -> lg==0 atomicMax
#pragma unroll
        for (int nf = 0; nf < 4; ++nf) {
            float m = fmaxf(fmaxf(fabsf(acc[nf][0]), fabsf(acc[nf][1])),
                            fmaxf(fabsf(acc[nf][2]), fabsf(acc[nf][3])));
            m = fmaxf(m, __shfl_xor(m, 16));
            m = fmaxf(m, __shfl_xor(m, 32));
            if (lg == 0) atomicMax(&smx[nf * 16 + l15], __float_as_int(m));
        }
        __syncthreads();

        // quantize from registers, 4B swizzled write into hs8
#pragma unroll
        for (int nf = 0; nf < 4; ++nf) {
            int row = nf * 16 + l15;
            float m2 = __int_as_float(smx[row]);
            float rs = (m2 > 1e-20f) ? 127.0f * __builtin_amdgcn_rcpf(m2) : 0.f;
            uint32_t packed = 0;
#pragma unroll
            for (int r = 0; r < 4; ++r) {
                int q = (int)__builtin_rintf(acc[nf][r] * rs);
                q = q > 127 ? 127 : (q < -127 ? -127 : q);
                packed |= ((uint32_t)(q & 255)) << (8 * r);
            }
            int col = (wave * 16 + lg * 4) ^ ((row & 7) << 4);
            *(uint32_t*)(hs8 + row * 128 + col) = packed;
        }
        __syncthreads();

        // copy-out: 512 threads x 16B = 8KB; plus stripe scales
        {
            int row = tid >> 3, c16 = (tid & 7) << 4;
            uint4 v = *(const uint4*)(hs8 + row * 128 + (c16 ^ ((row & 7) << 4)));
            long node = nb + row;
            if (node < NNODES)
                *(uint4*)((char*)UV8 + node * 512 + p * 128 + c16) = v;
        }
        if (tid < 64) {
            long node = nb + tid;
            if (node < NNODES)
                Sq[node * 4 + p] = __int_as_float(smx[tid]) * (1.0f / 127.0f);
        }
        // next pass's first sync separates hs8/smx reuse
    }
}

// =================== phase 2: pred = W2.relu(su*u8 + sv*v8 + b1) + b2 ===================
// 4 pairs per wave (16 lanes each); lane loads 16B of u and v (16 hc).
__launch_bounds__(512)
__global__ void pair_pred8(const int8_t* __restrict__ UV8,
                           const float* __restrict__ Sq,
                           const int* __restrict__ junc,
                           const float* __restrict__ b1, const float* __restrict__ w2,
                           const float* __restrict__ b2, float* __restrict__ out) {
    int tid = threadIdx.x;
    int l15 = tid & 15;
    long qid = (((long)blockIdx.x * 512 + tid) >> 4);   // 0..32767
    int st = l15 >> 3;                                   // stripe within half
    float b1c[16], w2c[16];
#pragma unroll
    for (int e = 0; e < 16; ++e) {
        int col = l15 * 16 + e;
        b1c[e] = b1[col];
        w2c[e] = w2[col];
    }
    float b2v = b2[0];
    for (long p = qid; p < NPAIRS; p += 32768) {
        int2 ij = ((const int2*)junc)[p];
        uint4 u4 = *(const uint4*)(UV8 + (long)ij.x * 512 + l15 * 16);
        uint4 v4 = *(const uint4*)(UV8 + (long)ij.y * 512 + 256 + l15 * 16);
        float su = Sq[ij.x * 4 + st];
        float sv = Sq[ij.y * 4 + 2 + st];
        float s = 0.f;
#define DEC(ud, vd, eb)                                                        \
        {                                                                      \
            _Pragma("unroll")                                                  \
            for (int b = 0; b < 4; ++b) {                                      \
                int ub = (int)((ud) << (24 - 8 * b)) >> 24;                    \
                int vb = (int)((vd) << (24 - 8 * b)) >> 24;                    \
                float h = fmaf(su, (float)ub, fmaf(sv, (float)vb, b1c[(eb) + b])); \
                s = fmaf(fmaxf(h, 0.f), w2c[(eb) + b], s);                     \
            }                                                                  \
        }
        DEC(u4.x, v4.x, 0)
        DEC(u4.y, v4.y, 4)
        DEC(u4.z, v4.z, 8)
        DEC(u4.w, v4.w, 12)
#undef DEC
        s += __shfl_xor(s, 1);
        s += __shfl_xor(s, 2);
        s += __shfl_xor(s, 4);
        s += __shfl_xor(s, 8);
        if (l15 == 0) out[p] = s + b2v;
    }
}

// =================== fallback (small ws): fused, known-correct ===================
__global__ void pack_w1(const float* __restrict__ W1, bf16* __restrict__ w1f) {
    int t = blockIdx.x * 256 + threadIdx.x;
    int lane = t & 63;
    int kk = (t >> 6) & 7;
    int cg = t >> 9;
    int l15 = lane & 15, lg = lane >> 4;
    bf16x8 v;
#pragma unroll
    for (int j = 0; j < 8; ++j)
        v[j] = (bf16)W1[(long)(kk * 32 + lg * 8 + j) * D2 + cg * 16 + l15];
    *(bf16x8*)((char*)w1f + ((long)t << 4)) = v;
}

__launch_bounds__(512, 2)
__global__ void fused_fb(const float* __restrict__ x, const int* __restrict__ junc,
                         const bf16* __restrict__ w1f, const float* __restrict__ b1,
                         const float* __restrict__ w2p, const float* __restrict__ b2,
                         float* __restrict__ out) {
    __shared__ char  atile[128 * 512];
    __shared__ float outp[4][128];
    int tid  = threadIdx.x;
    int wave = tid >> 6, lane = tid & 63;
    int l15 = lane & 15, lg = lane >> 4;
    int wr = wave >> 2, wc = wave & 3;
    long base_p = (long)blockIdx.x * 128;

    float bb[4][4], ww[4][4];
#pragma unroll
    for (int m = 0; m < 4; ++m)
#pragma unroll
        for (int r = 0; r < 4; ++r) {
            int hc = wc * 64 + m * 16 + lg * 4 + r;
            bb[m][r] = b1[hc];
            ww[m][r] = w2p[hc];
        }
#pragma unroll
    for (int it = 0; it < 8; ++it) {
        int task  = it * 512 + tid;
        int nr = task >> 4, chunk = task & 15;
        int r = nr >> 1, side = nr & 1;
        long p = base_p + r;
        int idx = (p < NPAIRS) ? junc[p * 2 + side] : 0;
        const float4* src = (const float4*)(x + (long)idx * DIM + chunk * 8);
        float4 a = src[0], b = src[1];
        bf16x8 v;
        v[0]=(bf16)a.x; v[1]=(bf16)a.y; v[2]=(bf16)a.z; v[3]=(bf16)a.w;
        v[4]=(bf16)b.x; v[5]=(bf16)b.y; v[6]=(bf16)b.z; v[7]=(bf16)b.w;
        int bir = side * 256 + chunk * 16;
        *(bf16x8*)(atile + r * 512 + (bir ^ ((r & 31) << 4))) = v;
    }
    __syncthreads();

    f32x4 acc[4][4];
#pragma unroll
    for (int m = 0; m < 4; ++m)
#pragma unroll
        for (int n = 0; n < 4; ++n)
            acc[m][n] = (f32x4){0.f, 0.f, 0.f, 0.f};
#pragma unroll
    for (int kk = 0; kk < 8; ++kk) {
        bf16x8 xf[4];
        int kbyte = kk * 64 + lg * 16;
#pragma unroll
        for (int n = 0; n < 4; ++n) {
            int r = wr * 64 + n * 16 + l15;
            xf[n] = *(const bf16x8*)(atile + r * 512 + (kbyte ^ ((r & 31) << 4)));
        }
#pragma unroll
        for (int m = 0; m < 4; ++m) {
            bf16x8 wf = *(const bf16x8*)((const char*)w1f +
                            ((((wc * 4 + m) * 8 + kk) * 64 + lane) << 4));
#pragma unroll
            for (int n = 0; n < 4; ++n)
                acc[m][n] = __builtin_amdgcn_mfma_f32_16x16x32_bf16(wf, xf[n], acc[m][n], 0, 0, 0);
        }
    }
#pragma unroll
    for (int n = 0; n < 4; ++n) {
        float s = 0.f;
#pragma unroll
        for (int m = 0; m < 4; ++m)
#pragma unroll
            for (int r = 0; r < 4; ++r)
                s = fmaf(fmaxf(acc[m][n][r] + bb[m][r], 0.f), ww[m][r], s);
        s += __shfl_xor(s, 16);
        s += __shfl_xor(s, 32);
        if (lg == 0) outp[wc][wr * 64 + n * 16 + l15] = s;
    }
    __syncthreads();
    if (tid < 128) {
        long p = base_p + tid;
        if (p < NPAIRS)
            out[p] = b2[0] + outp[0][tid] + outp[1][tid] + outp[2][tid] + outp[3][tid];
    }
}

extern "C" void kernel_launch(void* const* d_in, const int* in_sizes, int n_in,
                              void* d_out, int out_size, void* d_ws, size_t ws_size,
                              hipStream_t stream) {
    const float* x    = (const float*)d_in[0];
    const int*   junc = (const int*)  d_in[1];
    const float* W1   = (const float*)d_in[2];
    const float* b1   = (const float*)d_in[3];
    const float* W2   = (const float*)d_in[4];
    const float* b2   = (const float*)d_in[5];
    float* out = (float*)d_out;

    const size_t UV8_B = (size_t)NNODES * 512;        // 51,200,000
    const size_t SQ_B  = (size_t)NNODES * 16;         // 1,600,000
    const size_t NEED  = UV8_B + SQ_B + 131072;       // ~52.9 MB

    if (ws_size >= NEED) {
        char* base = (char*)d_ws;
        int8_t* UV8 = (int8_t*)base;
        float*  Sq  = (float*)(base + UV8_B);
        bf16*   w1p = (bf16*) (base + UV8_B + SQ_B);
        hipLaunchKernelGGL(pack_w1p, dim3(32), dim3(256), 0, stream, W1, w1p);
        hipLaunchKernelGGL(gemm_uvq, dim3((NNODES + 63) / 64), dim3(512), 0, stream,
                           x, w1p, UV8, Sq);
        hipLaunchKernelGGL(pair_pred8, dim3(1024), dim3(512), 0, stream,
                           UV8, Sq, junc, b1, W2, b2, out);
    } else {
        bf16* w1f = (bf16*)d_ws;
        hipLaunchKernelGGL(pack_w1, dim3(32), dim3(256), 0, stream, W1, w1f);
        hipLaunchKernelGGL(fused_fb, dim3((NPAIRS + 127) / 128), dim3(512), 0, stream,
                           x, junc, w1f, b1, W2, b2, out);
    }
}